// Round 1
// baseline (257.558 us; speedup 1.0000x reference)
//
#include <hip/hip_runtime.h>

// Problem constants
#define BB      8
#define DIMD    1024
#define NTOK    4096
#define CC      6
#define TN      64            // n-columns per block tile
#define NWAVE   8             // waves per block
#define NTHREADS (NWAVE * 64) // 512
#define RPW     (DIMD / NWAVE) // 128 d-rows per wave

__global__ __launch_bounds__(NTHREADS, 2)
void lq_fused(const float* __restrict__ z,  const float* __restrict__ Wi,
              const float* __restrict__ bi, const float* __restrict__ Wo,
              const float* __restrict__ bo, float* __restrict__ out,
              float* __restrict__ idx_out,  float* __restrict__ loss_out)
{
    // partials: [wave][nn][14] padded to 15 floats -> stride 15 (odd) => conflict-free
    __shared__ float part[NWAVE][TN][15];
    __shared__ float qs[CC][TN];
    __shared__ float redw[NWAVE];

    const int t    = threadIdx.x;
    const int lane = t & 63;
    const int wv   = t >> 6;
    const int blk  = blockIdx.x;
    const int b    = blk >> 6;          // 64 n-tiles per batch
    const int n0   = (blk & 63) << 6;   // * TN

    const int dbase = wv * RPW;
    const size_t zoff = ((size_t)b * DIMD + (size_t)dbase) * NTOK + (size_t)n0 + (size_t)lane;
    const float* zp = z + zoff;

    // ---------------- pass 1: accumulate x (Wi.z), y (Wo^T.z), bo.z, z.z ----------
    float xa0 = 0.f, xa1 = 0.f, xa2 = 0.f, xa3 = 0.f, xa4 = 0.f, xa5 = 0.f;
    float ya0 = 0.f, ya1 = 0.f, ya2 = 0.f, ya3 = 0.f, ya4 = 0.f, ya5 = 0.f;
    float zbp = 0.f, zzp = 0.f;

    #pragma unroll 4
    for (int i = 0; i < RPW; ++i) {
        const int d = __builtin_amdgcn_readfirstlane(dbase + i); // wave-uniform -> s_loads
        const float zv = zp[(size_t)i * NTOK];                   // coalesced 256B/wave
        const float* wir = Wi + d;        // Wi[c*DIMD + d]
        const float* wor = Wo + d * CC;   // Wo[d*CC + c]
        xa0 = fmaf(zv, wir[0 * DIMD], xa0);
        xa1 = fmaf(zv, wir[1 * DIMD], xa1);
        xa2 = fmaf(zv, wir[2 * DIMD], xa2);
        xa3 = fmaf(zv, wir[3 * DIMD], xa3);
        xa4 = fmaf(zv, wir[4 * DIMD], xa4);
        xa5 = fmaf(zv, wir[5 * DIMD], xa5);
        ya0 = fmaf(zv, wor[0], ya0);
        ya1 = fmaf(zv, wor[1], ya1);
        ya2 = fmaf(zv, wor[2], ya2);
        ya3 = fmaf(zv, wor[3], ya3);
        ya4 = fmaf(zv, wor[4], ya4);
        ya5 = fmaf(zv, wor[5], ya5);
        zbp = fmaf(zv, bo[d], zbp);
        zzp = fmaf(zv, zv, zzp);
    }

    {
        float* pw = &part[wv][lane][0];
        pw[0] = xa0; pw[1] = xa1; pw[2]  = xa2; pw[3]  = xa3; pw[4]  = xa4; pw[5]  = xa5;
        pw[6] = ya0; pw[7] = ya1; pw[8]  = ya2; pw[9]  = ya3; pw[10] = ya4; pw[11] = ya5;
        pw[12] = zbp; pw[13] = zzp;
    }
    __syncthreads();

    // ---------------- finalize + quantize (one thread per n-column) ----------------
    float lossA = 0.f;
    if (t < TN) {
        float X0 = bi[0], X1 = bi[1], X2 = bi[2], X3 = bi[3], X4 = bi[4], X5 = bi[5];
        float Y0 = 0.f, Y1 = 0.f, Y2 = 0.f, Y3 = 0.f, Y4 = 0.f, Y5 = 0.f;
        float ZB = 0.f, ZZ = 0.f;
        #pragma unroll
        for (int w = 0; w < NWAVE; ++w) {
            const float* pr = &part[w][t][0];
            X0 += pr[0]; X1 += pr[1]; X2 += pr[2];  X3 += pr[3];  X4 += pr[4];  X5 += pr[5];
            Y0 += pr[6]; Y1 += pr[7]; Y2 += pr[8];  Y3 += pr[9];  Y4 += pr[10]; Y5 += pr[11];
            ZB += pr[12]; ZZ += pr[13];
        }
        float idxf  = 0.f;
        float cross = ZB;
        float basis = 1.f;
        #define QSTEP(Xc, Yc, cidx)                                             \
        {                                                                       \
            float lv = rintf(fmaf((Xc), 8.f, 4.f));                             \
            lv = fminf(fmaxf(lv, 0.f), 7.f);                                    \
            float q = fmaf(lv, 0.125f, -0.5f);                                  \
            qs[cidx][t] = q;                                                    \
            cross = fmaf(q, (Yc), cross);                                       \
            idxf  = fmaf(lv, basis, idxf);                                      \
            basis *= 8.f;                                                       \
        }
        QSTEP(X0, Y0, 0) QSTEP(X1, Y1, 1) QSTEP(X2, Y2, 2)
        QSTEP(X3, Y3, 3) QSTEP(X4, Y4, 4) QSTEP(X5, Y5, 5)
        #undef QSTEP

        idx_out[b * NTOK + n0 + t] = idxf;        // integer-valued float, exact (< 2^24)
        lossA = ZZ - 2.f * cross;                 // sum z^2 - 2 sum out*z (this column)
        #pragma unroll
        for (int o = 32; o; o >>= 1) lossA += __shfl_down(lossA, o); // wave 0 only
    }
    __syncthreads();

    // ---------------- pass 2: out = Wo.q + bo, accumulate sum out^2 ----------------
    const float qv0 = qs[0][lane], qv1 = qs[1][lane], qv2 = qs[2][lane];
    const float qv3 = qs[3][lane], qv4 = qs[4][lane], qv5 = qs[5][lane];

    float lossB = 0.f;
    float* op = out + zoff;
    #pragma unroll 4
    for (int i = 0; i < RPW; ++i) {
        const int d = __builtin_amdgcn_readfirstlane(dbase + i);
        const float* wor = Wo + d * CC;
        float o = bo[d];
        o = fmaf(qv0, wor[0], o);
        o = fmaf(qv1, wor[1], o);
        o = fmaf(qv2, wor[2], o);
        o = fmaf(qv3, wor[3], o);
        o = fmaf(qv4, wor[4], o);
        o = fmaf(qv5, wor[5], o);
        op[(size_t)i * NTOK] = o;                 // coalesced 256B/wave
        lossB = fmaf(o, o, lossB);
    }
    #pragma unroll
    for (int o = 32; o; o >>= 1) lossB += __shfl_down(lossB, o);
    if (lane == 0) redw[wv] = lossB;
    __syncthreads();

    if (t == 0) {
        float s = lossA;                           // reduced wave-0 value (lane 0)
        #pragma unroll
        for (int w = 0; w < NWAVE; ++w) s += redw[w];
        atomicAdd(loss_out, s * (0.2f / 33554432.f));
    }
}

extern "C" void kernel_launch(void* const* d_in, const int* in_sizes, int n_in,
                              void* d_out, int out_size, void* d_ws, size_t ws_size,
                              hipStream_t stream) {
    const float* z  = (const float*)d_in[0];
    const float* Wi = (const float*)d_in[1];
    const float* bi = (const float*)d_in[2];
    const float* Wo = (const float*)d_in[3];
    const float* bo = (const float*)d_in[4];
    // d_in[5] = vals (uniform levels l/8 - 0.5) -- encoded analytically in the kernel

    float* out   = (float*)d_out;
    float* idxp  = out + (size_t)BB * DIMD * NTOK;   // 33554432
    float* lossp = idxp + (size_t)BB * NTOK;         // +32768

    // zero the loss accumulator (graph-capture-safe async memset on stream)
    hipMemsetAsync(lossp, 0, sizeof(float), stream);

    dim3 grid(BB * (NTOK / TN));   // 512 blocks
    lq_fused<<<grid, NTHREADS, 0, stream>>>(z, Wi, bi, Wo, bo, out, idxp, lossp);
}